// Round 22
// baseline (325.666 us; speedup 1.0000x reference)
//
#include <hip/hip_runtime.h>
#include <stdint.h>

// ---------------------------------------------------------------------------
// SNN forward — PASSING realization (R15/R18/R19/R20): BLIS KC=512 GEMM fold
// (two independent 512-K FMA-chain panels + fadd fold), exact-f32 scan,
// 8-lane mod-8 gemv tree for cur2. DO NOT change any arithmetic op or order.
// R21: issue-count reduction, bit-exact.
//   - phase1: 2 neurons/lane (lo=64w+lane, hi=+128) -> packed-f32 pairs the
//     3 dependent FP ops (v_pk_*), 2 rows/block, 2048 blocks = single
//     residency round. Ballot words / sbuf layout identical to R20.
//   - fc1 GEMM: double-buffered LDS, one barrier per KC chunk.
//   - phase2/phase3 unchanged from R20.
// B=4096, n_inp=1024, n_hid=256, T=1024, beta=f32(0.9), THR=1.
// ---------------------------------------------------------------------------

#define GEMM_TILE 64
#define GEMM_KC 16

// One 512-K panel per block (blockIdx.z selects panel) — single FMA chain.
__global__ __launch_bounds__(256) void fc1_gemm_panel(
    const float* __restrict__ x, const float* __restrict__ W1,
    float* __restrict__ p1, float* __restrict__ p2) {
  constexpr int K = 1024, N = 256, KP = 512;
  __shared__ float As[2][GEMM_KC][GEMM_TILE + 4];
  __shared__ float Ws[2][GEMM_KC][GEMM_TILE + 4];

  const int tid = threadIdx.x;
  const int b0 = blockIdx.x * GEMM_TILE;
  const int h0 = blockIdx.y * GEMM_TILE;
  const int kbase = blockIdx.z * KP;
  float* __restrict__ outp = blockIdx.z ? p2 : p1;

  const int tx = tid & 15;
  const int ty = tid >> 4;
  const int srow = tid >> 2;
  const int scol = (tid & 3) << 2;

  const float* xp = x + (size_t)(b0 + srow) * K + kbase + scol;
  const float* wp = W1 + (size_t)(h0 + srow) * K + kbase + scol;

  // Prologue: stage chunk 0 into buffer 0.
  float4 av = *reinterpret_cast<const float4*>(xp);
  float4 wv = *reinterpret_cast<const float4*>(wp);
  As[0][scol + 0][srow] = av.x; As[0][scol + 1][srow] = av.y;
  As[0][scol + 2][srow] = av.z; As[0][scol + 3][srow] = av.w;
  Ws[0][scol + 0][srow] = wv.x; Ws[0][scol + 1][srow] = wv.y;
  Ws[0][scol + 2][srow] = wv.z; Ws[0][scol + 3][srow] = wv.w;
  __syncthreads();

  float acc[4][4] = {};  // fresh ascending-k FMA chain (one 512 panel)
  int cur = 0;

  for (int kc = 0; kc < KP; kc += GEMM_KC) {
    const bool more = (kc + GEMM_KC < KP);
    if (more) {  // prefetch next chunk while computing current
      av = *reinterpret_cast<const float4*>(xp + kc + GEMM_KC);
      wv = *reinterpret_cast<const float4*>(wp + kc + GEMM_KC);
    }
#pragma unroll
    for (int kk = 0; kk < GEMM_KC; ++kk) {
      float4 a4 = *reinterpret_cast<const float4*>(&As[cur][kk][ty << 2]);
      float4 w4 = *reinterpret_cast<const float4*>(&Ws[cur][kk][tx << 2]);
      float af[4] = {a4.x, a4.y, a4.z, a4.w};
      float wf[4] = {w4.x, w4.y, w4.z, w4.w};
#pragma unroll
      for (int i = 0; i < 4; ++i)
#pragma unroll
        for (int j = 0; j < 4; ++j)
          acc[i][j] = fmaf(af[i], wf[j], acc[i][j]);  // BLIS vfmadd ukr
    }
    if (more) {
      const int nxt = cur ^ 1;
      As[nxt][scol + 0][srow] = av.x; As[nxt][scol + 1][srow] = av.y;
      As[nxt][scol + 2][srow] = av.z; As[nxt][scol + 3][srow] = av.w;
      Ws[nxt][scol + 0][srow] = wv.x; Ws[nxt][scol + 1][srow] = wv.y;
      Ws[nxt][scol + 2][srow] = wv.z; Ws[nxt][scol + 3][srow] = wv.w;
      __syncthreads();  // buffer nxt ready; all readers of cur are done
      cur = nxt;
    }
  }

#pragma unroll
  for (int i = 0; i < 4; ++i) {
    float4 o = make_float4(acc[i][0], acc[i][1], acc[i][2], acc[i][3]);
    *reinterpret_cast<float4*>(
        &outp[(size_t)(b0 + (ty << 2) + i) * N + h0 + (tx << 2)]) = o;
  }
}

// -------- Phase 1: layer-1 LIF; 2 neurons/lane, ballot via LDS stripes -----
// Block = 2 rows x 2 waves. Wave (r,w): lane l owns h_lo=64w+l (ballot word
// w) and h_hi=128+64w+l (ballot word w+2). c = fadd(fadd(p1,p2), b1) = BLIS
// panel fold + bias. sbuf layout [b][word][t] u64 — identical to R20.
// The two neurons' FP chains are independent -> compiler packs into v_pk_*.
__global__ __launch_bounds__(256) void snn_phase1(
    const float* __restrict__ p1, const float* __restrict__ p2,
    const float* __restrict__ b1, float* __restrict__ mem1buf,
    unsigned long long* __restrict__ sbuf, int t0, int tc) {
  __shared__ unsigned long long lds[2][4][64];
  const int tid = threadIdx.x;
  const int lane = tid & 63;
  const int w = (tid >> 6) & 1;   // word (lo) within row
  const int r = tid >> 7;         // row within block
  const int b = (blockIdx.x << 1) + r;
  const int hlo = (w << 6) + lane;
  const int hhi = hlo + 128;

  const float cA =
      __fadd_rn(__fadd_rn(p1[b * 256 + hlo], p2[b * 256 + hlo]), b1[hlo]);
  const float cB =
      __fadd_rn(__fadd_rn(p1[b * 256 + hhi], p2[b * 256 + hhi]), b1[hhi]);
  float mA = (t0 == 0) ? 0.0f : mem1buf[b * 256 + hlo];
  float mB = (t0 == 0) ? 0.0f : mem1buf[b * 256 + hhi];
  float spA = (mA > 1.0f) ? 1.0f : 0.0f;  // reset_t = H(mem_{t-1} - 1)
  float spB = (mB > 1.0f) ? 1.0f : 0.0f;

  unsigned long long* __restrict__ wbA = sbuf + (size_t)(b * 4 + w) * tc;
  unsigned long long* __restrict__ wbB = sbuf + (size_t)(b * 4 + w + 2) * tc;

  for (int tb = 0; tb < tc; tb += 64) {
#pragma unroll
    for (int u = 0; u < 64; ++u) {
      // Independent pair -> v_pk_mul / v_pk_add / v_pk_add(neg) candidates.
      mA = __fsub_rn(__fadd_rn(__fmul_rn(mA, 0.9f), cA), spA);
      mB = __fsub_rn(__fadd_rn(__fmul_rn(mB, 0.9f), cB), spB);
      const bool sA = mA > 1.0f;
      const bool sB = mB > 1.0f;
      const unsigned long long balA = __ballot(sA);
      const unsigned long long balB = __ballot(sB);
      spA = sA ? 1.0f : 0.0f;
      spB = sB ? 1.0f : 0.0f;
      if (lane == 0) {
        lds[r][w][u] = balA;      // wave-uniform, 1-lane DS write
        lds[r][w + 2][u] = balB;
      }
    }
    // Same-wave DS ordering: compiler inserts lgkmcnt wait before the reads.
    wbA[tb + lane] = lds[r][w][lane];      // coalesced 512B store
    wbB[tb + lane] = lds[r][w + 2][lane];  // coalesced 512B store
  }
  mem1buf[b * 256 + hlo] = mA;
  mem1buf[b * 256 + hhi] = mB;
}

// -------- Phase 2: cur2 dot (unchanged arithmetic), coalesced I/O ----------
__global__ __launch_bounds__(256) void snn_phase2(
    const unsigned long long* __restrict__ sbuf, const float* __restrict__ W2,
    float* __restrict__ cur2ws, int t0, int tc, int tcshift) {
  const int id = blockIdx.x * 256 + threadIdx.x;  // 4096 * tc lanes
  const int b = id >> tcshift;
  const int tl = id & (tc - 1);

  uint32_t wd[8];
#pragma unroll
  for (int w = 0; w < 4; ++w) {
    const unsigned long long v = sbuf[(size_t)(b * 4 + w) * tc + tl];
    wd[2 * w] = (uint32_t)v;
    wd[2 * w + 1] = (uint32_t)(v >> 32);
  }
  const int* w2i = reinterpret_cast<const int*>(W2);  // uniform -> s_loads

  float p[8] = {0.f, 0.f, 0.f, 0.f, 0.f, 0.f, 0.f, 0.f};
#pragma unroll
  for (int j = 0; j < 32; ++j) {
#pragma unroll
    for (int l = 0; l < 8; ++l) {
      const int h = 8 * j + l;
      const int mask = -(int)((wd[h >> 5] >> (h & 31)) & 1u);
      p[l] = __fadd_rn(p[l], __int_as_float(mask & w2i[h]));
    }
  }
  const float q0 = __fadd_rn(p[0], p[4]);
  const float q1 = __fadd_rn(p[1], p[5]);
  const float q2 = __fadd_rn(p[2], p[6]);
  const float q3 = __fadd_rn(p[3], p[7]);
  const float acc = __fadd_rn(__fadd_rn(q0, q2), __fadd_rn(q1, q3));

  cur2ws[(size_t)b * 1024 + (t0 + tl)] = acc;
}

// -------- Phase 3: mem2 scan; 16-t rolling float4 prefetch -----------------
__global__ __launch_bounds__(64) void snn_phase3(
    const float* __restrict__ cur2ws, const float* __restrict__ b2,
    float* __restrict__ out) {
  const int b = blockIdx.x * 64 + threadIdx.x;  // 4096 = 64 blocks x 64
  const float b2s = b2[0];
  float m2 = 0.0f, sp2 = 0.0f;
  float* __restrict__ outm = out;
  float* __restrict__ outs = out + (size_t)1024 * 4096;
  const float4* __restrict__ s4 =
      reinterpret_cast<const float4*>(cur2ws + (size_t)b * 1024);  // 256 f4

  float4 b0 = s4[0], b1v = s4[1], b2v = s4[2], b3 = s4[3];

#define SCAN4(V, TBASE)                                               \
  {                                                                   \
    const float vals[4] = {V.x, V.y, V.z, V.w};                       \
    _Pragma("unroll") for (int u = 0; u < 4; ++u) {                   \
      const size_t idx = (size_t)((TBASE) + u) * 4096 + b;            \
      const float cur2 = __fadd_rn(vals[u], b2s);                     \
      m2 = __fsub_rn(__fadd_rn(__fmul_rn(m2, 0.9f), cur2), sp2);      \
      const bool s = m2 > 1.0f;                                       \
      outm[idx] = m2;                                                 \
      const float sf = s ? 1.0f : 0.0f;                               \
      outs[idx] = sf;                                                 \
      sp2 = sf;                                                       \
    }                                                                 \
  }

  for (int g = 0; g < 63; ++g) {  // 63 groups of 16 t, prefetch next group
    const float4 c0 = b0, c1 = b1v, c2 = b2v, c3 = b3;
    const int nb = (g + 1) * 4;
    b0 = s4[nb + 0]; b1v = s4[nb + 1]; b2v = s4[nb + 2]; b3 = s4[nb + 3];
    const int tb = g * 16;
    SCAN4(c0, tb); SCAN4(c1, tb + 4); SCAN4(c2, tb + 8); SCAN4(c3, tb + 12);
  }
  SCAN4(b0, 1008); SCAN4(b1v, 1012); SCAN4(b2v, 1016); SCAN4(b3, 1020);
#undef SCAN4
}

// ---------------------------------------------------------------------------
extern "C" void kernel_launch(void* const* d_in, const int* in_sizes, int n_in,
                              void* d_out, int out_size, void* d_ws,
                              size_t ws_size, hipStream_t stream) {
  const float* x = (const float*)d_in[0];    // [4096,1024]
  const float* W1 = (const float*)d_in[1];   // [256,1024]
  const float* b1 = (const float*)d_in[2];   // [256]
  const float* W2 = (const float*)d_in[3];   // [1,256]
  const float* b2 = (const float*)d_in[4];   // [1]
  float* out = (float*)d_out;                // [2,1024,4096]

  constexpr int T = 1024, B = 4096;
  float* p1buf = (float*)d_ws;                                  // [0,4) MB
  float* p2buf = (float*)((char*)d_ws + (4u << 20));            // [4,8) MB
  float* mem1buf = (float*)((char*)d_ws + (8u << 20));          // [8,12) MB
  float* cur2ws = (float*)((char*)d_ws + (12u << 20));          // [12,28) MB
  unsigned long long* sbuf =
      (unsigned long long*)((char*)d_ws + (28u << 20));         // spike words

  // Tc = largest power of two (64..1024) with 128KB*Tc fitting after 28MB.
  size_t avail = (ws_size > (size_t)(28u << 20)) ? ws_size - (28u << 20) : 0;
  int Tc = 64, shift = 6;
  while (Tc < T && (size_t)(Tc * 2) * (B * 32) <= avail) { Tc <<= 1; ++shift; }

  dim3 gemm_grid(B / GEMM_TILE, 256 / GEMM_TILE, 2);
  fc1_gemm_panel<<<gemm_grid, 256, 0, stream>>>(x, W1, p1buf, p2buf);

  for (int t0 = 0; t0 < T; t0 += Tc) {
    const int tc = (T - t0 < Tc) ? (T - t0) : Tc;
    snn_phase1<<<B / 2, 256, 0, stream>>>(p1buf, p2buf, b1, mem1buf, sbuf, t0,
                                          tc);
    snn_phase2<<<(B / 256) * tc, 256, 0, stream>>>(sbuf, W2, cur2ws, t0, tc,
                                                   shift);
  }
  snn_phase3<<<B / 64, 64, 0, stream>>>(cur2ws, b2, out);
}

// Round 23
// 252.509 us; speedup vs baseline: 1.2897x; 1.2897x over previous
//
#include <hip/hip_runtime.h>
#include <stdint.h>

// ---------------------------------------------------------------------------
// SNN forward — PASSING realization (R15/R18/R19/R20): BLIS KC=512 GEMM fold
// (two independent 512-K FMA-chain panels + fadd fold), exact-f32 scan,
// 8-lane mod-8 gemv tree for cur2. DO NOT change any arithmetic op or order.
// R22: phase1 reverted to R20 decomposition (1 neuron/lane, 4096 blocks;
// R21's 2-neuron packing regressed) + per-iter transport eliminated:
//   - each lane accumulates its neuron's spike bits into a 64-bit column
//     (2 VALU/iter, no ballot/exec-dance/DS),
//   - every 64 t: in-register 64x64 bit transpose (shfl_xor butterfly,
//     stages 32,16,8,4,2,1) -> lane t holds word[t] -> same coalesced store
//     and sbuf layout as R20. Spike values bit-identical.
// B=4096, n_inp=1024, n_hid=256, T=1024, beta=f32(0.9), THR=1.
// ---------------------------------------------------------------------------

#define GEMM_TILE 64
#define GEMM_KC 16

// One 512-K panel per block (blockIdx.z selects panel) — single FMA chain.
__global__ __launch_bounds__(256) void fc1_gemm_panel(
    const float* __restrict__ x, const float* __restrict__ W1,
    float* __restrict__ p1, float* __restrict__ p2) {
  constexpr int K = 1024, N = 256, KP = 512;
  __shared__ float As[2][GEMM_KC][GEMM_TILE + 4];
  __shared__ float Ws[2][GEMM_KC][GEMM_TILE + 4];

  const int tid = threadIdx.x;
  const int b0 = blockIdx.x * GEMM_TILE;
  const int h0 = blockIdx.y * GEMM_TILE;
  const int kbase = blockIdx.z * KP;
  float* __restrict__ outp = blockIdx.z ? p2 : p1;

  const int tx = tid & 15;
  const int ty = tid >> 4;
  const int srow = tid >> 2;
  const int scol = (tid & 3) << 2;

  const float* xp = x + (size_t)(b0 + srow) * K + kbase + scol;
  const float* wp = W1 + (size_t)(h0 + srow) * K + kbase + scol;

  float4 av = *reinterpret_cast<const float4*>(xp);
  float4 wv = *reinterpret_cast<const float4*>(wp);
  As[0][scol + 0][srow] = av.x; As[0][scol + 1][srow] = av.y;
  As[0][scol + 2][srow] = av.z; As[0][scol + 3][srow] = av.w;
  Ws[0][scol + 0][srow] = wv.x; Ws[0][scol + 1][srow] = wv.y;
  Ws[0][scol + 2][srow] = wv.z; Ws[0][scol + 3][srow] = wv.w;
  __syncthreads();

  float acc[4][4] = {};  // fresh ascending-k FMA chain (one 512 panel)
  int cur = 0;

  for (int kc = 0; kc < KP; kc += GEMM_KC) {
    const bool more = (kc + GEMM_KC < KP);
    if (more) {
      av = *reinterpret_cast<const float4*>(xp + kc + GEMM_KC);
      wv = *reinterpret_cast<const float4*>(wp + kc + GEMM_KC);
    }
#pragma unroll
    for (int kk = 0; kk < GEMM_KC; ++kk) {
      float4 a4 = *reinterpret_cast<const float4*>(&As[cur][kk][ty << 2]);
      float4 w4 = *reinterpret_cast<const float4*>(&Ws[cur][kk][tx << 2]);
      float af[4] = {a4.x, a4.y, a4.z, a4.w};
      float wf[4] = {w4.x, w4.y, w4.z, w4.w};
#pragma unroll
      for (int i = 0; i < 4; ++i)
#pragma unroll
        for (int j = 0; j < 4; ++j)
          acc[i][j] = fmaf(af[i], wf[j], acc[i][j]);  // BLIS vfmadd ukr
    }
    if (more) {
      const int nxt = cur ^ 1;
      As[nxt][scol + 0][srow] = av.x; As[nxt][scol + 1][srow] = av.y;
      As[nxt][scol + 2][srow] = av.z; As[nxt][scol + 3][srow] = av.w;
      Ws[nxt][scol + 0][srow] = wv.x; Ws[nxt][scol + 1][srow] = wv.y;
      Ws[nxt][scol + 2][srow] = wv.z; Ws[nxt][scol + 3][srow] = wv.w;
      __syncthreads();
      cur = nxt;
    }
  }

#pragma unroll
  for (int i = 0; i < 4; ++i) {
    float4 o = make_float4(acc[i][0], acc[i][1], acc[i][2], acc[i][3]);
    *reinterpret_cast<float4*>(
        &outp[(size_t)(b0 + (ty << 2) + i) * N + h0 + (tx << 2)]) = o;
  }
}

// One butterfly stage of the 32x32 sub-transpose (within one u32 word).
__device__ __forceinline__ uint32_t xstage(uint32_t v, int S, uint32_t M,
                                           bool even) {
  const uint32_t y = (uint32_t)__shfl_xor((int)v, S, 64);
  const uint32_t a = (v & ~M) | ((y << S) & M);   // (lane&S)==0 result
  const uint32_t b = (v & M) | ((y & M) >> S);    // (lane&S)!=0 result
  return even ? a : b;
}

// -------- Phase 1: layer-1 LIF; bit-columns + register bit-transpose -------
// Block = 1 batch row, wave w owns neurons 64w..64w+63 (lane = neuron).
// Per iter (7 VALU, no DS/SALU): LIF core + accumulate own spike bit.
// Per 64 t: 64x64 bit transpose across lanes -> lane t holds word[t] ->
// coalesced 512B store. sbuf layout [b][w][t] u64 — identical to R20.
__global__ __launch_bounds__(256) void snn_phase1(
    const float* __restrict__ p1, const float* __restrict__ p2,
    const float* __restrict__ b1, float* __restrict__ mem1buf,
    unsigned long long* __restrict__ sbuf, int t0, int tc) {
  const int b = blockIdx.x;
  const int h = threadIdx.x;
  const int lane = h & 63;
  const int w = h >> 6;
  const float c =
      __fadd_rn(__fadd_rn(p1[b * 256 + h], p2[b * 256 + h]), b1[h]);
  float m = (t0 == 0) ? 0.0f : mem1buf[b * 256 + h];
  float sp = (m > 1.0f) ? 1.0f : 0.0f;  // reset_t = H(mem_{t-1} - 1)

  unsigned long long* __restrict__ wbase = sbuf + (size_t)(b * 4 + w) * tc;

  // Hoisted stage-parity predicates (loop-invariant -> sgpr masks).
  const bool e32 = (lane < 32);
  const bool e16 = ((lane & 16) == 0);
  const bool e8 = ((lane & 8) == 0);
  const bool e4 = ((lane & 4) == 0);
  const bool e2 = ((lane & 2) == 0);
  const bool e1 = ((lane & 1) == 0);

  for (int tb = 0; tb < tc; tb += 64) {
    uint32_t lo = 0u, hi = 0u;  // bit u = spike(t = tb+u / tb+32+u)
#pragma unroll
    for (int u = 0; u < 32; ++u) {
      m = __fsub_rn(__fadd_rn(__fmul_rn(m, 0.9f), c), sp);
      const bool s = m > 1.0f;
      sp = s ? 1.0f : 0.0f;
      const uint32_t t = lo | (1u << u);
      lo = s ? t : lo;
    }
#pragma unroll
    for (int u = 0; u < 32; ++u) {
      m = __fsub_rn(__fadd_rn(__fmul_rn(m, 0.9f), c), sp);
      const bool s = m > 1.0f;
      sp = s ? 1.0f : 0.0f;
      const uint32_t t = hi | (1u << u);
      hi = s ? t : hi;
    }

    // ---- 64x64 bit transpose across lanes (M[l][u] -> W[t] bit l) ----
    {  // stage 32: swap TR/BL 32x32 blocks between lane l and l^32
      const uint32_t ylo = (uint32_t)__shfl_xor((int)lo, 32, 64);
      const uint32_t yhi = (uint32_t)__shfl_xor((int)hi, 32, 64);
      const uint32_t nlo = e32 ? lo : yhi;
      const uint32_t nhi = e32 ? ylo : hi;
      lo = nlo;
      hi = nhi;
    }
    lo = xstage(lo, 16, 0xFFFF0000u, e16); hi = xstage(hi, 16, 0xFFFF0000u, e16);
    lo = xstage(lo, 8, 0xFF00FF00u, e8);   hi = xstage(hi, 8, 0xFF00FF00u, e8);
    lo = xstage(lo, 4, 0xF0F0F0F0u, e4);   hi = xstage(hi, 4, 0xF0F0F0F0u, e4);
    lo = xstage(lo, 2, 0xCCCCCCCCu, e2);   hi = xstage(hi, 2, 0xCCCCCCCCu, e2);
    lo = xstage(lo, 1, 0xAAAAAAAAu, e1);   hi = xstage(hi, 1, 0xAAAAAAAAu, e1);

    // lane t now holds word[t=tb+t]: bit l = spike(neuron 64w+l, t).
    wbase[tb + lane] =
        ((unsigned long long)hi << 32) | (unsigned long long)lo;
  }
  mem1buf[b * 256 + h] = m;
}

// -------- Phase 2: cur2 dot (unchanged arithmetic), coalesced I/O ----------
__global__ __launch_bounds__(256) void snn_phase2(
    const unsigned long long* __restrict__ sbuf, const float* __restrict__ W2,
    float* __restrict__ cur2ws, int t0, int tc, int tcshift) {
  const int id = blockIdx.x * 256 + threadIdx.x;  // 4096 * tc lanes
  const int b = id >> tcshift;
  const int tl = id & (tc - 1);

  uint32_t wd[8];
#pragma unroll
  for (int w = 0; w < 4; ++w) {
    const unsigned long long v = sbuf[(size_t)(b * 4 + w) * tc + tl];
    wd[2 * w] = (uint32_t)v;
    wd[2 * w + 1] = (uint32_t)(v >> 32);
  }
  const int* w2i = reinterpret_cast<const int*>(W2);  // uniform -> s_loads

  float p[8] = {0.f, 0.f, 0.f, 0.f, 0.f, 0.f, 0.f, 0.f};
#pragma unroll
  for (int j = 0; j < 32; ++j) {
#pragma unroll
    for (int l = 0; l < 8; ++l) {
      const int h = 8 * j + l;
      const int mask = -(int)((wd[h >> 5] >> (h & 31)) & 1u);
      p[l] = __fadd_rn(p[l], __int_as_float(mask & w2i[h]));
    }
  }
  const float q0 = __fadd_rn(p[0], p[4]);
  const float q1 = __fadd_rn(p[1], p[5]);
  const float q2 = __fadd_rn(p[2], p[6]);
  const float q3 = __fadd_rn(p[3], p[7]);
  const float acc = __fadd_rn(__fadd_rn(q0, q2), __fadd_rn(q1, q3));

  cur2ws[(size_t)b * 1024 + (t0 + tl)] = acc;
}

// -------- Phase 3: mem2 scan; 16-t rolling float4 prefetch -----------------
__global__ __launch_bounds__(64) void snn_phase3(
    const float* __restrict__ cur2ws, const float* __restrict__ b2,
    float* __restrict__ out) {
  const int b = blockIdx.x * 64 + threadIdx.x;  // 4096 = 64 blocks x 64
  const float b2s = b2[0];
  float m2 = 0.0f, sp2 = 0.0f;
  float* __restrict__ outm = out;
  float* __restrict__ outs = out + (size_t)1024 * 4096;
  const float4* __restrict__ s4 =
      reinterpret_cast<const float4*>(cur2ws + (size_t)b * 1024);  // 256 f4

  float4 b0 = s4[0], b1v = s4[1], b2v = s4[2], b3 = s4[3];

#define SCAN4(V, TBASE)                                               \
  {                                                                   \
    const float vals[4] = {V.x, V.y, V.z, V.w};                       \
    _Pragma("unroll") for (int u = 0; u < 4; ++u) {                   \
      const size_t idx = (size_t)((TBASE) + u) * 4096 + b;            \
      const float cur2 = __fadd_rn(vals[u], b2s);                     \
      m2 = __fsub_rn(__fadd_rn(__fmul_rn(m2, 0.9f), cur2), sp2);      \
      const bool s = m2 > 1.0f;                                       \
      outm[idx] = m2;                                                 \
      const float sf = s ? 1.0f : 0.0f;                               \
      outs[idx] = sf;                                                 \
      sp2 = sf;                                                       \
    }                                                                 \
  }

  for (int g = 0; g < 63; ++g) {  // 63 groups of 16 t, prefetch next group
    const float4 c0 = b0, c1 = b1v, c2 = b2v, c3 = b3;
    const int nb = (g + 1) * 4;
    b0 = s4[nb + 0]; b1v = s4[nb + 1]; b2v = s4[nb + 2]; b3 = s4[nb + 3];
    const int tb = g * 16;
    SCAN4(c0, tb); SCAN4(c1, tb + 4); SCAN4(c2, tb + 8); SCAN4(c3, tb + 12);
  }
  SCAN4(b0, 1008); SCAN4(b1v, 1012); SCAN4(b2v, 1016); SCAN4(b3, 1020);
#undef SCAN4
}

// ---------------------------------------------------------------------------
extern "C" void kernel_launch(void* const* d_in, const int* in_sizes, int n_in,
                              void* d_out, int out_size, void* d_ws,
                              size_t ws_size, hipStream_t stream) {
  const float* x = (const float*)d_in[0];    // [4096,1024]
  const float* W1 = (const float*)d_in[1];   // [256,1024]
  const float* b1 = (const float*)d_in[2];   // [256]
  const float* W2 = (const float*)d_in[3];   // [1,256]
  const float* b2 = (const float*)d_in[4];   // [1]
  float* out = (float*)d_out;                // [2,1024,4096]

  constexpr int T = 1024, B = 4096;
  float* p1buf = (float*)d_ws;                                  // [0,4) MB
  float* p2buf = (float*)((char*)d_ws + (4u << 20));            // [4,8) MB
  float* mem1buf = (float*)((char*)d_ws + (8u << 20));          // [8,12) MB
  float* cur2ws = (float*)((char*)d_ws + (12u << 20));          // [12,28) MB
  unsigned long long* sbuf =
      (unsigned long long*)((char*)d_ws + (28u << 20));         // spike words

  // Tc = largest power of two (64..1024) with 128KB*Tc fitting after 28MB.
  size_t avail = (ws_size > (size_t)(28u << 20)) ? ws_size - (28u << 20) : 0;
  int Tc = 64, shift = 6;
  while (Tc < T && (size_t)(Tc * 2) * (B * 32) <= avail) { Tc <<= 1; ++shift; }

  dim3 gemm_grid(B / GEMM_TILE, 256 / GEMM_TILE, 2);
  fc1_gemm_panel<<<gemm_grid, 256, 0, stream>>>(x, W1, p1buf, p2buf);

  for (int t0 = 0; t0 < T; t0 += Tc) {
    const int tc = (T - t0 < Tc) ? (T - t0) : Tc;
    snn_phase1<<<B, 256, 0, stream>>>(p1buf, p2buf, b1, mem1buf, sbuf, t0, tc);
    snn_phase2<<<(B / 256) * tc, 256, 0, stream>>>(sbuf, W2, cur2ws, t0, tc,
                                                   shift);
  }
  snn_phase3<<<B / 64, 64, 0, stream>>>(cur2ws, b2, out);
}